// Round 1
// baseline (1623.484 us; speedup 1.0000x reference)
//
#include <hip/hip_runtime.h>

#define TSZ (1u << 19)
#define HPRIME 2654435761u

__device__ __forceinline__ float sigmoidf(float x) {
    return 1.0f / (1.0f + __expf(-x));
}

// Transpose W_tiny (32x65 row-major) -> WT (65x32 row-major) so the per-output-
// column dot product reads 16B-aligned float4s (stride 65 rows are unaligned).
__global__ void repack_w(const float* __restrict__ W, float* __restrict__ WT) {
    int t = blockIdx.x * blockDim.x + threadIdx.x;
    if (t < 65 * 32) {
        int j = t >> 5, k = t & 31;
        WT[j * 32 + k] = W[k * 65 + j];
    }
}

__global__ __launch_bounds__(256)
void sdf_main(const float* __restrict__ in,
              const float* __restrict__ tables,
              const float* __restrict__ Wp1,
              const float* __restrict__ Wp2,
              const float* __restrict__ Wp3,
              const float* __restrict__ bt,
              const float* __restrict__ WT,
              float* __restrict__ out,
              int N)
{
    __shared__ float sOut[256 * 17];  // 17-stride pad: 2-way banks only (free)
    const int tid = threadIdx.x;
    const long long n0 = (long long)blockIdx.x * 256;
    const int n = (int)n0 + tid;
    const int nc = n < N ? n : N - 1;

    const float px = in[nc * 3 + 0];
    const float py = in[nc * 3 + 1];
    const float pz = in[nc * 3 + 2];

    // ---------------- prior net (frequency enc -> 64 -> 64 -> 1) ----------------
    const float PIF = 3.14159274101257324e+00f;  // float32(np.pi); 2x/4x exact
    float e[12];
    {
        float a0 = px * PIF, a1 = px * (2.0f * PIF), a2 = px * (4.0f * PIF);
        float b0 = py * PIF, b1 = py * (2.0f * PIF), b2 = py * (4.0f * PIF);
        e[0] = sinf(a0); e[1]  = sinf(a1); e[2]  = sinf(a2);
        e[3] = cosf(a0); e[4]  = cosf(a1); e[5]  = cosf(a2);
        e[6] = sinf(b0); e[7]  = sinf(b1); e[8]  = sinf(b2);
        e[9] = cosf(b0); e[10] = cosf(b1); e[11] = cosf(b2);
    }

    float h[64];
#pragma unroll
    for (int j4 = 0; j4 < 64; j4 += 4) {   // fully unrolled: h[] stays in VGPRs
        float s0 = 0.f, s1 = 0.f, s2 = 0.f, s3 = 0.f;
#pragma unroll
        for (int k = 0; k < 12; k++) {
            const float4 w = *(const float4*)(Wp1 + k * 64 + j4);
            s0 += e[k] * w.x; s1 += e[k] * w.y; s2 += e[k] * w.z; s3 += e[k] * w.w;
        }
        h[j4 + 0] = sigmoidf(s0);
        h[j4 + 1] = sigmoidf(s1);
        h[j4 + 2] = sigmoidf(s2);
        h[j4 + 3] = sigmoidf(s3);
    }

    float prior = 0.f;
    for (int j4 = 0; j4 < 64; j4 += 4) {   // h2 never materialized; fuse into Wp3 dot
        float s0 = 0.f, s1 = 0.f, s2 = 0.f, s3 = 0.f;
#pragma unroll
        for (int k = 0; k < 64; k++) {
            const float4 w = *(const float4*)(Wp2 + k * 64 + j4);
            s0 += h[k] * w.x; s1 += h[k] * w.y; s2 += h[k] * w.z; s3 += h[k] * w.w;
        }
        const float4 p = *(const float4*)(Wp3 + j4);
        prior += p.x * sigmoidf(s0) + p.y * sigmoidf(s1)
               + p.z * sigmoidf(s2) + p.w * sigmoidf(s3);
    }

    // ---------------- hash-grid encode ----------------
    // scale = 1.5^l * 16 - 1 (all exactly fp32-representable); res = ceil(scale)+1
    // dense iff res*res <= 2^19  ->  levels 0..9 dense, 10..15 hashed.
    const float scl[16] = {15.f, 23.f, 35.f, 53.f, 80.f, 120.5f, 181.25f, 272.375f,
                           409.0625f, 614.09375f, 921.640625f, 1382.9609375f,
                           2074.94140625f, 3112.912109375f, 4669.8681640625f,
                           7005.30224609375f};
    const int ress[10] = {16, 24, 36, 54, 81, 122, 183, 274, 411, 616};

    // explicit rn ops: match numpy mul-then-add (no fma contraction -> no floor flips)
    const float cx = __fadd_rn(__fdiv_rn(px, 30.0f), 0.5f);
    const float cy = __fadd_rn(__fdiv_rn(py, 30.0f), 0.5f);

    float f[32];
#pragma unroll
    for (int l = 0; l < 16; l++) {
        const float sc = scl[l];
        const float posx = __fadd_rn(__fmul_rn(cx, sc), 0.5f);
        const float posy = __fadd_rn(__fmul_rn(cy, sc), 0.5f);
        const float fx = floorf(posx), fy = floorf(posy);
        const float wx = __fsub_rn(posx, fx), wy = __fsub_rn(posy, fy);
        const int ix = (int)fx, iy = (int)fy;
        const float* tbl = tables + (size_t)l * (size_t)(TSZ * 2);
        int i00, i10, i01, i11;
        if (l < 10) {
            const int r = ress[l];
            i00 = ix + iy * r; i10 = i00 + 1; i01 = i00 + r; i11 = i01 + 1;
        } else {
            const unsigned ux = (unsigned)ix, uy = (unsigned)iy;
            const unsigned hy0 = uy * HPRIME, hy1 = (uy + 1u) * HPRIME;
            i00 = (int)((ux ^ hy0) & (TSZ - 1u));
            i10 = (int)(((ux + 1u) ^ hy0) & (TSZ - 1u));
            i01 = (int)((ux ^ hy1) & (TSZ - 1u));
            i11 = (int)(((ux + 1u) ^ hy1) & (TSZ - 1u));
        }
        const float2 q00 = *(const float2*)(tbl + 2 * i00);
        const float2 q10 = *(const float2*)(tbl + 2 * i10);
        const float2 q01 = *(const float2*)(tbl + 2 * i01);
        const float2 q11 = *(const float2*)(tbl + 2 * i11);
        const float omx = 1.0f - wx, omy = 1.0f - wy;
        f[2 * l]     = (q00.x * omx + q10.x * wx) * omy + (q01.x * omx + q11.x * wx) * wy;
        f[2 * l + 1] = (q00.y * omx + q10.y * wx) * omy + (q01.y * omx + q11.y * wx) * wy;
    }

    // ---------------- x = feat @ W_tiny + b; epilogue + coalesced store ----------
    // column 0 (scattered scalar store, 1/65 of traffic)
    {
        float s = bt[0];
#pragma unroll
        for (int k4 = 0; k4 < 32; k4 += 4) {
            const float4 w = *(const float4*)(WT + k4);
            s += f[k4] * w.x + f[k4 + 1] * w.y + f[k4 + 2] * w.z + f[k4 + 3] * w.w;
        }
        if (n < N) out[(size_t)n * 65] = pz - s - prior;
    }

    // columns 1..64 in 4 chunks of 16, staged through LDS for coalesced stores
    for (int ch = 0; ch < 4; ch++) {
        const int jb = 1 + ch * 16;
        float v[16];
#pragma unroll
        for (int c = 0; c < 16; c++) {
            const int j = jb + c;
            float s = bt[j];
            const float* wr = WT + j * 32;
#pragma unroll
            for (int k4 = 0; k4 < 32; k4 += 4) {
                const float4 w = *(const float4*)(wr + k4);
                s += f[k4] * w.x + f[k4 + 1] * w.y + f[k4 + 2] * w.z + f[k4 + 3] * w.w;
            }
            v[c] = s;
        }
        __syncthreads();
#pragma unroll
        for (int c = 0; c < 16; c++) sOut[tid * 17 + c] = v[c];
        __syncthreads();
#pragma unroll
        for (int it = 0; it < 16; it++) {
            const int t = tid + it * 256;
            const int r = t >> 4, c = t & 15;
            const long long row = n0 + r;
            if (row < N) out[(size_t)row * 65 + jb + c] = sOut[r * 17 + c];
        }
    }
}

extern "C" void kernel_launch(void* const* d_in, const int* in_sizes, int n_in,
                              void* d_out, int out_size, void* d_ws, size_t ws_size,
                              hipStream_t stream) {
    const float* inputs = (const float*)d_in[0];
    const float* tables = (const float*)d_in[1];
    const float* W_tiny = (const float*)d_in[2];
    const float* b_tiny = (const float*)d_in[3];
    const float* Wp1    = (const float*)d_in[4];
    const float* Wp2    = (const float*)d_in[5];
    const float* Wp3    = (const float*)d_in[6];
    float* out = (float*)d_out;
    float* WT  = (float*)d_ws;  // 65*32 floats = 8320 B scratch

    const int N = in_sizes[0] / 3;

    hipLaunchKernelGGL(repack_w, dim3(9), dim3(256), 0, stream, W_tiny, WT);

    const int grid = (N + 255) / 256;
    hipLaunchKernelGGL(sdf_main, dim3(grid), dim3(256), 0, stream,
                       inputs, tables, Wp1, Wp2, Wp3, b_tiny, WT, out, N);
}

// Round 2
// 1017.447 us; speedup vs baseline: 1.5956x; 1.5956x over previous
//
#include <hip/hip_runtime.h>

#define TSZ (1u << 19)
#define HPRIME 2654435761u

typedef short bf16x8 __attribute__((ext_vector_type(8)));
typedef float f32x4 __attribute__((ext_vector_type(4)));

__device__ __forceinline__ float sigmoidf(float x) {
    return 1.0f / (1.0f + __expf(-x));
}

__device__ __forceinline__ unsigned short f2b(float f) {
    union { float f; unsigned u; } v; v.f = f;
    return (unsigned short)((v.u + 0x7FFFu + ((v.u >> 16) & 1u)) >> 16);
}

__device__ __forceinline__ unsigned f2b_pack(float a, float b) {
    union { float f; unsigned u; } x, y; x.f = a; y.f = b;
    unsigned ra = (x.u + 0x7FFFu + ((x.u >> 16) & 1u)) >> 16;
    unsigned rb = (y.u + 0x7FFFu + ((y.u >> 16) & 1u)) & 0xFFFF0000u;
    return ra | rb;
}

// Precompute B-operand MFMA fragments (bf16) for Wp2 (64x64) and W_tiny cols
// 1..64 (32x64). B layout for mfma_f32_16x16x32_bf16: lane holds
// B[k = (lane>>4)*8 + j][n = lane&15], j=0..7 contiguous in the 8-vector.
__global__ void repack_frags(const float* __restrict__ Wp2,
                             const float* __restrict__ Wt,
                             unsigned short* __restrict__ wp2F,
                             unsigned short* __restrict__ wtF) {
    int t = blockIdx.x * blockDim.x + threadIdx.x;
    if (t < 4096) {  // 8 frags (kstep*4+ntile) x 64 lanes x 8
        int j = t & 7, lane = (t >> 3) & 63, f = t >> 9;
        int ks = f >> 2, nt = f & 3;
        int k = ks * 32 + (lane >> 4) * 8 + j;
        int n = nt * 16 + (lane & 15);
        wp2F[t] = f2b(Wp2[k * 64 + n]);
    }
    if (t < 2048) {  // 4 frags (ntile) x 64 lanes x 8, K=32
        int j = t & 7, lane = (t >> 3) & 63, nt = t >> 9;
        int k = (lane >> 4) * 8 + j;
        int n = nt * 16 + (lane & 15);
        wtF[t] = f2b(Wt[k * 65 + 1 + n]);
    }
}

__global__ __launch_bounds__(256)
void sdf_main(const float* __restrict__ in,
              const float* __restrict__ tables,
              const float* __restrict__ Wp1,
              const float* __restrict__ Wp3,
              const float* __restrict__ bt,
              const float* __restrict__ Wt,
              const unsigned short* __restrict__ wp2F,
              const unsigned short* __restrict__ wtF,
              float* __restrict__ out, int N)
{
    // Per-wave A-staging buffer, stride 72 bf16 (144 B: 16B-aligned rows, ~2-way
    // banks on b128 frag reads). featBuf (stride 40) overlays the SAME wave's
    // region (wave-private, in-order DS ops -> no cross-wave hazard).
    __shared__ unsigned short Abuf[4 * 64 * 72];  // 36864 B
    __shared__ float sOut[64 * 65];               // 16640 B, epilogue tile
    __shared__ float sPrior[256];                 // 1024 B

    const int tid = threadIdx.x;
    const int wave = tid >> 6, lane = tid & 63;
    const int quad = lane >> 4, col = lane & 15;
    const long long n0 = (long long)blockIdx.x * 256;
    const int n = (int)n0 + tid;
    const int nc = n < N ? n : N - 1;

    const float px = in[nc * 3 + 0];
    const float py = in[nc * 3 + 1];
    const float pz = in[nc * 3 + 2];

    // ---------------- frequency encoding ----------------
    const float PIF = 3.14159274101257324e+00f;
    float e[12];
    e[0] = __sinf(px * PIF); e[1]  = __sinf(px * (2.0f * PIF)); e[2]  = __sinf(px * (4.0f * PIF));
    e[3] = __cosf(px * PIF); e[4]  = __cosf(px * (2.0f * PIF)); e[5]  = __cosf(px * (4.0f * PIF));
    e[6] = __sinf(py * PIF); e[7]  = __sinf(py * (2.0f * PIF)); e[8]  = __sinf(py * (4.0f * PIF));
    e[9] = __cosf(py * PIF); e[10] = __cosf(py * (2.0f * PIF)); e[11] = __cosf(py * (4.0f * PIF));

    // ---------------- layer1 (VALU, 768 FMA) -> h bf16 into Abuf A-layout ------
    unsigned short* myA = Abuf + wave * 64 * 72 + lane * 72;
#pragma unroll
    for (int j4 = 0; j4 < 64; j4 += 4) {
        float s0 = 0.f, s1 = 0.f, s2 = 0.f, s3 = 0.f;
#pragma unroll
        for (int k = 0; k < 12; k++) {
            const float4 w = *(const float4*)(Wp1 + k * 64 + j4);
            s0 += e[k] * w.x; s1 += e[k] * w.y; s2 += e[k] * w.z; s3 += e[k] * w.w;
        }
        uint2 pk;
        pk.x = f2b_pack(sigmoidf(s0), sigmoidf(s1));
        pk.y = f2b_pack(sigmoidf(s2), sigmoidf(s3));
        *reinterpret_cast<uint2*>(myA + j4) = pk;
    }
    __syncthreads();

    // ---------------- layer2 via MFMA (M=64 pts, K=64, N=64) + prior reduce ----
    bf16x8 bfr[8];
#pragma unroll
    for (int f = 0; f < 8; f++)
        bfr[f] = *reinterpret_cast<const bf16x8*>(wp2F + (f * 64 + lane) * 8);
    float w3[4];
#pragma unroll
    for (int nt = 0; nt < 4; nt++) w3[nt] = Wp3[nt * 16 + col];

#pragma unroll
    for (int mt = 0; mt < 4; mt++) {
        const unsigned short* ar = Abuf + wave * 4608 + (mt * 16 + col) * 72;
        const bf16x8 a0 = *reinterpret_cast<const bf16x8*>(ar + quad * 8);
        const bf16x8 a1 = *reinterpret_cast<const bf16x8*>(ar + 32 + quad * 8);
        float pp[4] = {0.f, 0.f, 0.f, 0.f};
#pragma unroll
        for (int nt = 0; nt < 4; nt++) {
            f32x4 acc = {0.f, 0.f, 0.f, 0.f};
            acc = __builtin_amdgcn_mfma_f32_16x16x32_bf16(a0, bfr[nt], acc, 0, 0, 0);
            acc = __builtin_amdgcn_mfma_f32_16x16x32_bf16(a1, bfr[4 + nt], acc, 0, 0, 0);
#pragma unroll
            for (int r = 0; r < 4; r++)
                pp[r] += w3[nt] * sigmoidf(acc[r]);
        }
#pragma unroll
        for (int r = 0; r < 4; r++) {   // sum over the 16 cols of the group
            pp[r] += __shfl_xor(pp[r], 1, 64);
            pp[r] += __shfl_xor(pp[r], 2, 64);
            pp[r] += __shfl_xor(pp[r], 4, 64);
            pp[r] += __shfl_xor(pp[r], 8, 64);
            if (col == r) sPrior[wave * 64 + mt * 16 + quad * 4 + r] = pp[r];
        }
    }

    // ---------------- hash gather (fp32) -> featBuf bf16 + x0 ------------------
    const float scl[16] = {15.f, 23.f, 35.f, 53.f, 80.f, 120.5f, 181.25f, 272.375f,
                           409.0625f, 614.09375f, 921.640625f, 1382.9609375f,
                           2074.94140625f, 3112.912109375f, 4669.8681640625f,
                           7005.30224609375f};
    const int ress[10] = {16, 24, 36, 54, 81, 122, 183, 274, 411, 616};
    const float cx = __fadd_rn(__fdiv_rn(px, 30.0f), 0.5f);
    const float cy = __fadd_rn(__fdiv_rn(py, 30.0f), 0.5f);

    unsigned short* myF = Abuf + wave * 4608 + lane * 40;  // overlay own wave's A region
    float x0 = bt[0];
    unsigned pk[4];
#pragma unroll
    for (int l = 0; l < 16; l++) {
        const float sc = scl[l];
        const float posx = __fadd_rn(__fmul_rn(cx, sc), 0.5f);
        const float posy = __fadd_rn(__fmul_rn(cy, sc), 0.5f);
        const float fx = floorf(posx), fy = floorf(posy);
        const float wx = __fsub_rn(posx, fx), wy = __fsub_rn(posy, fy);
        const int ix = (int)fx, iy = (int)fy;
        const float* tbl = tables + (size_t)l * (size_t)(TSZ * 2);
        int i00, i10, i01, i11;
        if (l < 10) {
            const int r = ress[l];
            i00 = ix + iy * r; i10 = i00 + 1; i01 = i00 + r; i11 = i01 + 1;
        } else {
            const unsigned ux = (unsigned)ix, uy = (unsigned)iy;
            const unsigned hy0 = uy * HPRIME, hy1 = (uy + 1u) * HPRIME;
            i00 = (int)((ux ^ hy0) & (TSZ - 1u));
            i10 = (int)(((ux + 1u) ^ hy0) & (TSZ - 1u));
            i01 = (int)((ux ^ hy1) & (TSZ - 1u));
            i11 = (int)(((ux + 1u) ^ hy1) & (TSZ - 1u));
        }
        const float2 q00 = *(const float2*)(tbl + 2 * i00);
        const float2 q10 = *(const float2*)(tbl + 2 * i10);
        const float2 q01 = *(const float2*)(tbl + 2 * i01);
        const float2 q11 = *(const float2*)(tbl + 2 * i11);
        const float omx = 1.0f - wx, omy = 1.0f - wy;
        const float f0 = (q00.x * omx + q10.x * wx) * omy + (q01.x * omx + q11.x * wx) * wy;
        const float f1 = (q00.y * omx + q10.y * wx) * omy + (q01.y * omx + q11.y * wx) * wy;
        x0 += f0 * Wt[(2 * l) * 65] + f1 * Wt[(2 * l + 1) * 65];
        pk[l & 3] = f2b_pack(f0, f1);
        if ((l & 3) == 3) {
            uint4 v; v.x = pk[0]; v.y = pk[1]; v.z = pk[2]; v.w = pk[3];
            *reinterpret_cast<uint4*>(myF + (l - 3) * 2) = v;
        }
    }
    __syncthreads();   // sPrior visibility across... (wave-private really; cheap)

    const float priorMe = sPrior[wave * 64 + lane];

    // ---------------- epilogue: W_tiny MFMA per wave-round + coalesced copy ----
    for (int q = 0; q < 4; q++) {
        if (wave == q) {
            bf16x8 fa[4];
#pragma unroll
            for (int mt = 0; mt < 4; mt++)
                fa[mt] = *reinterpret_cast<const bf16x8*>(
                    Abuf + wave * 4608 + (mt * 16 + col) * 40 + quad * 8);
#pragma unroll
            for (int nt = 0; nt < 4; nt++) {
                const bf16x8 wb = *reinterpret_cast<const bf16x8*>(wtF + (nt * 64 + lane) * 8);
                const float bb = bt[1 + nt * 16 + col];
#pragma unroll
                for (int mt = 0; mt < 4; mt++) {
                    f32x4 acc = {0.f, 0.f, 0.f, 0.f};
                    acc = __builtin_amdgcn_mfma_f32_16x16x32_bf16(fa[mt], wb, acc, 0, 0, 0);
#pragma unroll
                    for (int r = 0; r < 4; r++)
                        sOut[(mt * 16 + quad * 4 + r) * 65 + 1 + nt * 16 + col] = acc[r] + bb;
                }
            }
            sOut[lane * 65] = pz - x0 - priorMe;
        }
        __syncthreads();
        const long long rbase = n0 + (long long)q * 64;
        float* op = out + (size_t)rbase * 65;
#pragma unroll
        for (int i = 0; i < 17; i++) {
            const int t = tid + i * 256;
            if (t < 4160 && rbase + t / 65 < N) op[t] = sOut[t];
        }
        __syncthreads();
    }
}

extern "C" void kernel_launch(void* const* d_in, const int* in_sizes, int n_in,
                              void* d_out, int out_size, void* d_ws, size_t ws_size,
                              hipStream_t stream) {
    const float* inputs = (const float*)d_in[0];
    const float* tables = (const float*)d_in[1];
    const float* W_tiny = (const float*)d_in[2];
    const float* b_tiny = (const float*)d_in[3];
    const float* Wp1    = (const float*)d_in[4];
    const float* Wp2    = (const float*)d_in[5];
    const float* Wp3    = (const float*)d_in[6];
    float* out = (float*)d_out;
    unsigned short* wp2F = (unsigned short*)d_ws;        // 4096 bf16 = 8 KB
    unsigned short* wtF  = wp2F + 4096;                  // 2048 bf16 = 4 KB

    const int N = in_sizes[0] / 3;

    hipLaunchKernelGGL(repack_frags, dim3(16), dim3(256), 0, stream,
                       Wp2, W_tiny, wp2F, wtF);

    const int grid = (N + 255) / 256;
    hipLaunchKernelGGL(sdf_main, dim3(grid), dim3(256), 0, stream,
                       inputs, tables, Wp1, Wp3, b_tiny, W_tiny, wp2F, wtF, out, N);
}